// Round 1
// baseline (112494.849 us; speedup 1.0000x reference)
//
#include <hip/hip_runtime.h>

#define DEV __device__ __forceinline__

constexpr int Bb = 64, Tt = 512, Ii = 256, Hd = 512;
constexpr int NWG = 256, NTHR = 256;
constexpr int TM = 32, TN = 128;

// ---- workspace layout (in floats) ----
#define OFF_H   32
#define GP_SL   (Bb*2048)
#define OFF_GP  (OFF_H + Bb*Hd)              // 32800
#define FP_SL   (Bb*1024)
#define OFF_FP  (OFF_GP + 8*GP_SL)           // 1081376
#define CP_SL   (Bb*512)
#define OFF_CP  (OFF_FP + 16*FP_SL)          // 2129952
#define AHP_SL  (Bb*512)
#define OFF_AHP (OFF_CP + 16*CP_SL)          // 2654240
#define XP_SL   (Bb*256)
#define OFF_XP  (OFF_AHP + 8*AHP_SL)         // 2916384

#define SMEM_FLOATS (96*36 + 96*128)         // ldsA[96][36] + ldsW[96][128] = 15744
#define SMEM_BYTES  (SMEM_FLOATS*4)          // 62976

struct P {
  const float *tt, *mark;
  const float *Wxz_t, *Wxr_t, *Wxz_m, *Wxr_m, *Wxh;
  const float *Whz_t, *Whr_t, *Whz_m, *Whr_m, *Whh;
  const float *bz_t, *br_t, *bz_m, *br_m, *bh;
  const float *fWrt, *fWrm, *fWzt, *fWzm, *fWxt, *fWxm;
  const float *frb, *fzb, *fxb;
  float* out; float* ws;
};

enum { JG = 0, JF = 1, JC = 2, JAH = 3, JXM = 4 };

DEV float sig1(float x) { return 1.f / (1.f + __expf(-x)); }
DEV float tanh1(float x) { return 2.f * sig1(2.f * x) - 1.f; }
DEV float4 ld4(const float* p) { return *(const float4*)p; }
DEV float4 a4(float4 a, float4 b) { return make_float4(a.x+b.x, a.y+b.y, a.z+b.z, a.w+b.w); }
DEV float4 m4(float4 a, float4 b) { return make_float4(a.x*b.x, a.y*b.y, a.z*b.z, a.w*b.w); }
DEV float4 sig4(float4 v) { return make_float4(sig1(v.x), sig1(v.y), sig1(v.z), sig1(v.w)); }
DEV float4 tanh4(float4 v) { return make_float4(tanh1(v.x), tanh1(v.y), tanh1(v.z), tanh1(v.w)); }
DEV float4 mix4(float4 g, float4 x, float4 y) {  // g*x + (1-g)*y
  return make_float4(g.x*x.x + (1.f-g.x)*y.x, g.y*x.y + (1.f-g.y)*y.y,
                     g.z*x.z + (1.f-g.z)*y.z, g.w*x.w + (1.f-g.w)*y.w);
}

// A-operand generator: 4 consecutive k (k % 4 == 0, never straddles segment bounds)
DEV float4 loadA4(const P& p, int type, const float* aPtr, int side, int t, int b, int k) {
  const float* ws = p.ws;
  switch (type) {
    case JG: {
      if (k < Ii) return ld4(&aPtr[(b*Tt + t)*Ii + k]);
      return ld4(&ws[OFF_H + b*Hd + (k - Ii)]);
    }
    case JF: {
      const int lo = (k < 512);
      const int gc = (lo ? 0 : 512) + (side ? 512 : 0) + k;  // col in G matrix
      const float* bs = lo ? (side ? p.br_t : p.bz_t) : (side ? p.br_m : p.bz_m);
      float4 s = ld4(&bs[lo ? k : (k - 512)]);
      #pragma unroll
      for (int q = 0; q < 8; ++q) s = a4(s, ld4(&ws[OFF_GP + q*GP_SL + b*2048 + gc]));
      return sig4(s);
    }
    case JC: {
      float4 s = ld4(&p.frb[k]);
      #pragma unroll
      for (int q = 0; q < 16; ++q) s = a4(s, ld4(&ws[OFF_FP + q*FP_SL + b*1024 + 512 + k]));
      float4 r = sig4(s);
      s = ld4(&p.br_t[k]);
      #pragma unroll
      for (int q = 0; q < 8; ++q) s = a4(s, ld4(&ws[OFF_GP + q*GP_SL + b*2048 + 512 + k]));
      float4 Rt = sig4(s);
      s = ld4(&p.br_m[k]);
      #pragma unroll
      for (int q = 0; q < 8; ++q) s = a4(s, ld4(&ws[OFF_GP + q*GP_SL + b*2048 + 1536 + k]));
      float4 Rm = sig4(s);
      float4 R = mix4(r, Rt, Rm);
      return m4(R, ld4(&ws[OFF_H + b*Hd + k]));
    }
    case JAH: {
      float4 s = ld4(&p.fxb[k]);
      #pragma unroll
      for (int q = 0; q < 16; ++q) s = a4(s, ld4(&ws[OFF_XP + q*XP_SL + b*256 + k]));
      float4 xg = sig4(s);
      float4 xt = ld4(&p.tt[(b*Tt + t)*Ii + k]);
      float4 xm = ld4(&p.mark[(b*Tt + t)*Ii + k]);
      return mix4(xg, xt, xm);
    }
    default: {  // JXM
      if (k < Ii) return ld4(&p.tt[(b*Tt + t)*Ii + k]);
      return ld4(&p.mark[(b*Tt + t)*Ii + (k - Ii)]);
    }
  }
}

// One GEMM job: output tile [32 x 128] at (brow0, nco) of a partial slab, K-chunk [K0, K0+KC).
// 4 waves split K; per-thread 8x8 fp32 micro-tile; LDS tree reduction.
DEV void gemm_job(const P& p, float* sm, int type, int t,
                  const float* aPtr, int side,
                  int brow0, int K0, int KC,
                  const float* wA, int wSa, const float* wB, int wSb, int kSpl,
                  int ncw, float* oSlab, int oStr, int nco) {
  float* ldsA = sm;            // [KC][36]
  float* ldsW = sm + 96*36;    // [KC][128]
  const int tid = threadIdx.x;
  // ---- stage A ----
  {
    const int kq = KC >> 2;
    for (int idx = tid; idx < kq * TM; idx += NTHR) {
      const int m = idx / kq, k4 = idx - m * kq;
      const int k = K0 + (k4 << 2);
      float4 av = loadA4(p, type, aPtr, side, t, brow0 + m, k);
      float* d = &ldsA[(k4 << 2) * 36 + m];
      d[0] = av.x; d[36] = av.y; d[72] = av.z; d[108] = av.w;
    }
  }
  // ---- stage W ----
  for (int idx = tid; idx < (KC << 5); idx += NTHR) {
    const int kk = idx >> 5, nj = (idx & 31) << 2;
    const int k = K0 + kk, n = ncw + nj;
    float4 wv = (k < kSpl) ? ld4(&wA[k * wSa + n]) : ld4(&wB[(k - kSpl) * wSb + n]);
    *(float4*)&ldsW[(kk << 7) + nj] = wv;
  }
  __syncthreads();
  // ---- k-loop ----
  const int wv_ = tid >> 6, lane = tid & 63, mg = lane >> 4, ng = lane & 15;
  float acc[8][8];
  #pragma unroll
  for (int i = 0; i < 8; ++i)
    #pragma unroll
    for (int j = 0; j < 8; ++j) acc[i][j] = 0.f;
  const int kcw = KC >> 2;
  for (int kk = wv_ * kcw, ke = (wv_ + 1) * kcw; kk < ke; ++kk) {
    float4 a0 = ld4(&ldsA[kk*36 + (mg << 3)]);
    float4 a1 = ld4(&ldsA[kk*36 + (mg << 3) + 4]);
    float4 w0 = ld4(&ldsW[(kk << 7) + (ng << 3)]);
    float4 w1 = ld4(&ldsW[(kk << 7) + (ng << 3) + 4]);
    const float am[8] = {a0.x,a0.y,a0.z,a0.w,a1.x,a1.y,a1.z,a1.w};
    const float wn[8] = {w0.x,w0.y,w0.z,w0.w,w1.x,w1.y,w1.z,w1.w};
    #pragma unroll
    for (int mi = 0; mi < 8; ++mi)
      #pragma unroll
      for (int ni = 0; ni < 8; ++ni)
        acc[mi][ni] = fmaf(am[mi], wn[ni], acc[mi][ni]);
  }
  __syncthreads();
  // ---- reduce across 4 waves (red[2][32][128] aliases staging LDS) ----
  float* red = sm;
  if (wv_ < 2) {
    float* rb = &red[wv_ * 4096];
    #pragma unroll
    for (int mi = 0; mi < 8; ++mi) {
      float* q = &rb[((mg << 3) + mi) * 128 + (ng << 3)];
      *(float4*)q       = make_float4(acc[mi][0], acc[mi][1], acc[mi][2], acc[mi][3]);
      *(float4*)(q + 4) = make_float4(acc[mi][4], acc[mi][5], acc[mi][6], acc[mi][7]);
    }
  }
  __syncthreads();
  if (wv_ >= 2) {
    float* rb = &red[(wv_ - 2) * 4096];
    #pragma unroll
    for (int mi = 0; mi < 8; ++mi) {
      float* q = &rb[((mg << 3) + mi) * 128 + (ng << 3)];
      float4 c0 = ld4(q), c1 = ld4(q + 4);
      *(float4*)q       = make_float4(c0.x+acc[mi][0], c0.y+acc[mi][1], c0.z+acc[mi][2], c0.w+acc[mi][3]);
      *(float4*)(q + 4) = make_float4(c1.x+acc[mi][4], c1.y+acc[mi][5], c1.z+acc[mi][6], c1.w+acc[mi][7]);
    }
  }
  __syncthreads();
  // ---- write partial tile ----
  for (int e = tid; e < 1024; e += NTHR) {
    const int m = e >> 5, nq = (e & 31) << 2;
    float4 r0 = ld4(&red[(m << 7) + nq]);
    float4 r1 = ld4(&red[4096 + (m << 7) + nq]);
    *(float4*)&oSlab[(brow0 + m) * oStr + nco + nq] = a4(r0, r1);
  }
}

DEV void gbar(unsigned* cnt, unsigned* gen, unsigned target) {
  __syncthreads();
  if (threadIdx.x == 0) {
    __threadfence();
    unsigned arr = __hip_atomic_fetch_add(cnt, 1u, __ATOMIC_ACQ_REL, __HIP_MEMORY_SCOPE_AGENT);
    if (arr == NWG - 1) {
      __hip_atomic_store(cnt, 0u, __ATOMIC_RELAXED, __HIP_MEMORY_SCOPE_AGENT);
      __hip_atomic_fetch_add(gen, 1u, __ATOMIC_RELEASE, __HIP_MEMORY_SCOPE_AGENT);
    } else {
      while (__hip_atomic_load(gen, __ATOMIC_ACQUIRE, __HIP_MEMORY_SCOPE_AGENT) < target) {
        __builtin_amdgcn_s_sleep(1);
      }
    }
    __threadfence();
  }
  __syncthreads();
}

__global__ void ggru_init(float* ws) {
  const int i = blockIdx.x * 256 + threadIdx.x;
  if (i < OFF_H + Bb * Hd) ws[i] = 0.f;  // barrier words + H0 = 0
}

__global__ __launch_bounds__(NTHR)
void ggru_persist(P p) {
  extern __shared__ float sm[];
  const int wg = blockIdx.x, tid = threadIdx.x;
  float* ws = p.ws;
  unsigned* cnt = (unsigned*)ws;
  unsigned* gen = (unsigned*)ws + 16;
  unsigned target = 0;

  // ---- static per-WG job params ----
  // phase A: 256 jobs = 32 tiles x 8 k-slabs (KC=96, K=768 = [X(256)|H(512)])
  const int A_ks = wg & 7, A_tile = wg >> 3;
  const int A_mt = A_tile & 1, A_nt = A_tile >> 1;
  const int A_gate = A_nt >> 2, A_ncw = (A_nt & 3) * 128;
  const float* A_xin = (A_gate < 2) ? p.tt : p.mark;
  const float* A_wx = (A_gate == 0) ? p.Wxz_t : (A_gate == 1) ? p.Wxr_t : (A_gate == 2) ? p.Wxz_m : p.Wxr_m;
  const float* A_wh = (A_gate == 0) ? p.Whz_t : (A_gate == 1) ? p.Whr_t : (A_gate == 2) ? p.Whz_m : p.Whr_m;
  // phase B: 256 jobs = 16 tiles x 16 k-slabs (KC=64, K=1024)
  const int B_ks = wg & 15, B_tile = wg >> 4;
  const int B_mt = B_tile & 1, B_nt = B_tile >> 1;
  const int B_side = B_nt >> 2, B_ncw = (B_nt & 3) * 128;
  const float* B_wa = B_side ? p.fWrt : p.fWzt;
  const float* B_wb = B_side ? p.fWrm : p.fWzm;
  // phase C: wg<128 -> C jobs (8 tiles x 16 ks, KC=32, K=512); wg in [128,192) -> Ah jobs
  const int C_ks = wg & 15, C_tile = wg >> 4;
  const int C_mt = C_tile & 1, C_ncw = (C_tile >> 1) * 128;
  const int H2 = wg - 128;
  const int AH_ks = H2 & 7, AH_tile = H2 >> 3;
  const int AH_mt = AH_tile & 1, AH_ncw = (AH_tile >> 1) * 128;
  // PH phase xmix: wg<64 (4 tiles x 16 ks, KC=32, K=512)
  const int X_ks = wg & 15, X_tile = wg >> 4;
  const int X_mt = X_tile & 1, X_ncw = (X_tile >> 1) * 128;

  for (int t = 0; t <= Tt; ++t) {
    // ---------- phase PH: materialize H(t) + x-mix GEMM ----------
    if (t >= 1 && tid < 32) {
      const int b = wg >> 2;
      const int j = ((wg & 3) << 7) + (tid << 2);
      float4 s = ld4(&p.bz_t[j]);
      #pragma unroll
      for (int q = 0; q < 8; ++q) s = a4(s, ld4(&ws[OFF_GP + q*GP_SL + b*2048 + j]));
      float4 Zt = sig4(s);
      s = ld4(&p.bz_m[j]);
      #pragma unroll
      for (int q = 0; q < 8; ++q) s = a4(s, ld4(&ws[OFF_GP + q*GP_SL + b*2048 + 1024 + j]));
      float4 Zm = sig4(s);
      s = ld4(&p.fzb[j]);
      #pragma unroll
      for (int q = 0; q < 16; ++q) s = a4(s, ld4(&ws[OFF_FP + q*FP_SL + b*1024 + j]));
      float4 z = sig4(s);
      float4 Z = mix4(z, Zt, Zm);
      s = ld4(&p.bh[j]);
      #pragma unroll
      for (int q = 0; q < 16; ++q) s = a4(s, ld4(&ws[OFF_CP + q*CP_SL + b*512 + j]));
      #pragma unroll
      for (int q = 0; q < 8; ++q) s = a4(s, ld4(&ws[OFF_AHP + q*AHP_SL + b*512 + j]));
      float4 Ht = tanh4(s);
      float4 Ho = ld4(&ws[OFF_H + b*Hd + j]);
      float4 Hn = mix4(Z, Ho, Ht);
      *(float4*)&ws[OFF_H + b*Hd + j] = Hn;
      *(float4*)&p.out[(b*Tt + (t - 1))*Hd + j] = Hn;
      if (t == Tt) *(float4*)&p.out[Bb*Tt*Hd + b*Hd + j] = Hn;
    }
    if (t < Tt && wg < 64) {
      gemm_job(p, sm, JXM, t, nullptr, 0, X_mt*32, X_ks*32, 32,
               p.fWxt, 256, p.fWxm, 256, 256, X_ncw,
               ws + OFF_XP + X_ks*XP_SL, 256, X_ncw);
    }
    gbar(cnt, gen, ++target);
    if (t == Tt) break;
    // ---------- phase A: gate pre-activations ----------
    gemm_job(p, sm, JG, t, A_xin, 0, A_mt*32, A_ks*96, 96,
             A_wx, 512, A_wh, 512, 256, A_ncw,
             ws + OFF_GP + A_ks*GP_SL, 2048, A_gate*512 + A_ncw);
    gbar(cnt, gen, ++target);
    // ---------- phase B: fused z/r pre-activations ----------
    gemm_job(p, sm, JF, t, nullptr, B_side, B_mt*32, B_ks*64, 64,
             B_wa, 512, B_wb, 512, 512, B_ncw,
             ws + OFF_FP + B_ks*FP_SL, 1024, B_side*512 + B_ncw);
    gbar(cnt, gen, ++target);
    // ---------- phase C: (R*H)@W_hh and X@W_xh ----------
    if (wg < 128) {
      gemm_job(p, sm, JC, t, nullptr, 0, C_mt*32, C_ks*32, 32,
               p.Whh, 512, p.Whh, 512, 512, C_ncw,
               ws + OFF_CP + C_ks*CP_SL, 512, C_ncw);
    } else if (wg < 192) {
      gemm_job(p, sm, JAH, t, nullptr, 0, AH_mt*32, AH_ks*32, 32,
               p.Wxh, 512, p.Wxh, 512, 256, AH_ncw,
               ws + OFF_AHP + AH_ks*AHP_SL, 512, AH_ncw);
    }
    gbar(cnt, gen, ++target);
  }
}

extern "C" void kernel_launch(void* const* d_in, const int* in_sizes, int n_in,
                              void* d_out, int out_size, void* d_ws, size_t ws_size,
                              hipStream_t stream) {
  P pr;
  pr.tt    = (const float*)d_in[0];
  pr.mark  = (const float*)d_in[1];
  pr.Wxz_t = (const float*)d_in[2];
  pr.Wxr_t = (const float*)d_in[3];
  pr.Wxz_m = (const float*)d_in[4];
  pr.Wxr_m = (const float*)d_in[5];
  pr.Wxh   = (const float*)d_in[6];
  pr.Whz_t = (const float*)d_in[7];
  pr.Whr_t = (const float*)d_in[8];
  pr.Whz_m = (const float*)d_in[9];
  pr.Whr_m = (const float*)d_in[10];
  pr.Whh   = (const float*)d_in[11];
  pr.bz_t  = (const float*)d_in[12];
  pr.br_t  = (const float*)d_in[13];
  pr.bz_m  = (const float*)d_in[14];
  pr.br_m  = (const float*)d_in[15];
  pr.bh    = (const float*)d_in[16];
  pr.fWrt  = (const float*)d_in[17];
  pr.fWrm  = (const float*)d_in[18];
  pr.fWzt  = (const float*)d_in[19];
  pr.fWzm  = (const float*)d_in[20];
  pr.fWxt  = (const float*)d_in[21];
  pr.fWxm  = (const float*)d_in[22];
  pr.frb   = (const float*)d_in[23];
  pr.fzb   = (const float*)d_in[24];
  pr.fxb   = (const float*)d_in[25];
  pr.out = (float*)d_out;
  pr.ws  = (float*)d_ws;

  hipLaunchKernelGGL(ggru_init, dim3(129), dim3(256), 0, stream, (float*)d_ws);

  void* args[] = { (void*)&pr };
  hipError_t err = hipLaunchCooperativeKernel((const void*)ggru_persist,
                                              dim3(NWG), dim3(NTHR),
                                              args, (unsigned)SMEM_BYTES, stream);
  if (err != hipSuccess) {
    // fallback: 256 blocks of 63KB LDS are co-resident on 256 CUs anyway
    hipLaunchKernelGGL(ggru_persist, dim3(NWG), dim3(NTHR), SMEM_BYTES, stream, pr);
  }
}

// Round 2
// 18896.263 us; speedup vs baseline: 5.9533x; 5.9533x over previous
//
#include <hip/hip_runtime.h>

#define DEV __device__ __forceinline__

constexpr int Bb = 64, Tt = 512, Ii = 256, Hd = 512;
constexpr int NWG = 256, NTHR = 256;

// ---- workspace layout (floats) ----
// [0,1024): grid barrier (leaf[32] @ stride 16 uints, root @ uint 512, gen @ uint 544)
// [1024,2048): tile counters (60 × stride 16 uints): A:0-31 B:32-47 C:48-55 X:56-59
constexpr int OFF_TC = 1024;
constexpr int OFF_G  = 2048;                  // gates σ'd: [4][64][512] = 131072
constexpr int OFF_F  = OFF_G + 4 * Bb * Hd;   // z,r σ'd: [2][64][512] = 65536
constexpr int OFF_HB = OFF_F + 2 * Bb * Hd;   // H double-buffer: [2][64][512]
constexpr int OFF_XB = OFF_HB + 2 * Bb * Hd;  // X double-buffer: [2][64][256]
constexpr int OFF_PA = OFF_XB + 2 * Bb * Ii;  // A partials: 32 tiles × 8 × 4096
constexpr int OFF_PB = OFF_PA + 32 * 8 * 4096;// B partials: 16 × 16 × 4096
constexpr int OFF_PC = OFF_PB + 16 * 16 * 4096;// C partials: 8 × 8 × 4096
constexpr int OFF_PX = OFF_PC + 8 * 8 * 4096; // X partials: 4 × 8 × 4096
// end = 2787328 floats = 11.15 MB (< round-1's proven 12.7 MB ws use)

#define SMEM_BYTES (96*36*4 + 96*128*4)       // ldsA[96][36] + ldsW[96][128] = 62976 B

struct P {
  const float *tt, *mark;
  const float *Wxz_t, *Wxr_t, *Wxz_m, *Wxr_m, *Wxh;
  const float *Whz_t, *Whr_t, *Whz_m, *Whr_m, *Whh;
  const float *bz_t, *br_t, *bz_m, *br_m, *bh;
  const float *fWrt, *fWrm, *fWzt, *fWzm, *fWxt, *fWxm;
  const float *frb, *fzb, *fxb;
  float* out; float* ws;
};

enum { JA = 0, JB = 1, JCH = 2, JX = 3 };

DEV float sig1(float x) { return 1.f / (1.f + __expf(-x)); }
DEV float tanh1(float x) { return 2.f * sig1(2.f * x) - 1.f; }
DEV float4 ld4(const float* p) { return *(const float4*)p; }

// coherent (agent-scope, L2-bypass) 8B load/store — no cache maintenance emitted
DEV float2 ld2v(const float* p) {
  unsigned long long u = __hip_atomic_load((const unsigned long long*)p,
                                           __ATOMIC_RELAXED, __HIP_MEMORY_SCOPE_AGENT);
  return __builtin_bit_cast(float2, u);
}
DEV void st2v(float* p, float2 v) {
  __hip_atomic_store((unsigned long long*)p, __builtin_bit_cast(unsigned long long, v),
                     __ATOMIC_RELAXED, __HIP_MEMORY_SCOPE_AGENT);
}
DEV float4 ld4v(const float* p) {
  float2 a = ld2v(p), b = ld2v(p + 2);
  return make_float4(a.x, a.y, b.x, b.y);
}

// A-operand generator for 4 consecutive k (k%4==0; 4-groups never straddle segment bounds)
template<int TYPE>
DEV float4 loadA4(const P& p, int t, const float* aux, int side, int b, int k) {
  const float* ws = p.ws;
  if constexpr (TYPE == JA) {          // [X_raw(256) | H(t-1)(512)]
    if (k < Ii) return ld4(&aux[(b * Tt + (t - 1)) * Ii + k]);
    return ld4v(ws + OFF_HB + ((t - 1) & 1) * Bb * Hd + b * Hd + (k - Ii));
  } else if constexpr (TYPE == JB) {   // [Zt|Zm] (side0) or [Rt|Rm] (side1), σ'd finals
    const int g = (k < Hd) ? side : side + 2;
    const int j = (k < Hd) ? k : k - Hd;
    return ld4v(ws + OFF_G + g * Bb * Hd + b * Hd + j);
  } else if constexpr (TYPE == JCH) {  // [X_mixed(256) | (R·H)(512)]
    if (k < Ii) return ld4v(ws + OFF_XB + (t & 1) * Bb * Ii + b * Ii + k);
    const int base = b * Hd + (k - Ii);
    float4 r  = ld4v(ws + OFF_F  + 1 * Bb * Hd + base);
    float4 Rt = ld4v(ws + OFF_G  + 1 * Bb * Hd + base);
    float4 Rm = ld4v(ws + OFF_G  + 3 * Bb * Hd + base);
    float4 Ho = ld4v(ws + OFF_HB + ((t - 1) & 1) * Bb * Hd + base);
    float4 o;
    o.x = (r.x * Rt.x + (1.f - r.x) * Rm.x) * Ho.x;
    o.y = (r.y * Rt.y + (1.f - r.y) * Rm.y) * Ho.y;
    o.z = (r.z * Rt.z + (1.f - r.z) * Rm.z) * Ho.z;
    o.w = (r.w * Rt.w + (1.f - r.w) * Rm.w) * Ho.w;
    return o;
  } else {                             // JX: [Xt_raw | Xm_raw], input row t (for step t+1)
    if (k < Ii) return ld4(&p.tt[(b * Tt + t) * Ii + k]);
    return ld4(&p.mark[(b * Tt + t) * Ii + (k - Ii)]);
  }
}

// GEMM job: output tile [32 x 128], K-chunk [K0,K0+KC). 4 waves split KC; 8x8/lane;
// LDS tree reduce; partial tile -> partSlab (coherent stores).
template<int TYPE, int KC>
DEV void gemm_job(const P& p, float* sm, int t, const float* aux, int side,
                  int brow0, int n0, int K0,
                  const float* wA, int sA, const float* wB, int sB, int kSpl,
                  float* partSlab) {
  float* ldsA = sm;             // [KC][36]
  float* ldsW = sm + 96 * 36;   // [KC][128]
  const int tid = threadIdx.x;
  constexpr int kq = KC >> 2;
  // stage A
  for (int idx = tid; idx < (kq << 5); idx += NTHR) {
    const int m = idx / kq, k4 = idx - m * kq;
    const int k = K0 + (k4 << 2);
    float4 av = loadA4<TYPE>(p, t, aux, side, brow0 + m, k);
    float* d = &ldsA[(k4 << 2) * 36 + m];
    d[0] = av.x; d[36] = av.y; d[72] = av.z; d[108] = av.w;
  }
  // stage W (plain cached loads; weights stay per-XCD L2-resident)
  for (int idx = tid; idx < (KC << 5); idx += NTHR) {
    const int kk = idx >> 5, nj = (idx & 31) << 2;
    const int k = K0 + kk, n = n0 + nj;
    float4 wv = (k < kSpl) ? ld4(&wA[k * sA + n]) : ld4(&wB[(k - kSpl) * sB + n]);
    *(float4*)&ldsW[(kk << 7) + nj] = wv;
  }
  __syncthreads();
  // k-loop: 8x8 per lane
  const int wv_ = tid >> 6, lane = tid & 63, mg = lane >> 4, ng = lane & 15;
  float acc[8][8];
  #pragma unroll
  for (int i = 0; i < 8; ++i)
    #pragma unroll
    for (int j = 0; j < 8; ++j) acc[i][j] = 0.f;
  constexpr int kcw = KC >> 2;
  for (int kk = wv_ * kcw, ke = (wv_ + 1) * kcw; kk < ke; ++kk) {
    float4 a0 = ld4(&ldsA[kk * 36 + (mg << 3)]);
    float4 a1 = ld4(&ldsA[kk * 36 + (mg << 3) + 4]);
    float4 w0 = ld4(&ldsW[(kk << 7) + (ng << 3)]);
    float4 w1 = ld4(&ldsW[(kk << 7) + (ng << 3) + 4]);
    const float am[8] = {a0.x,a0.y,a0.z,a0.w,a1.x,a1.y,a1.z,a1.w};
    const float wn[8] = {w0.x,w0.y,w0.z,w0.w,w1.x,w1.y,w1.z,w1.w};
    #pragma unroll
    for (int mi = 0; mi < 8; ++mi)
      #pragma unroll
      for (int ni = 0; ni < 8; ++ni)
        acc[mi][ni] = fmaf(am[mi], wn[ni], acc[mi][ni]);
  }
  __syncthreads();
  // 4-wave LDS reduce: red[2][4096] aliases staging LDS
  float* red = sm;
  if (wv_ < 2) {
    float* rb = &red[wv_ * 4096];
    #pragma unroll
    for (int mi = 0; mi < 8; ++mi) {
      float* q = &rb[((mg << 3) + mi) * 128 + (ng << 3)];
      *(float4*)q       = make_float4(acc[mi][0], acc[mi][1], acc[mi][2], acc[mi][3]);
      *(float4*)(q + 4) = make_float4(acc[mi][4], acc[mi][5], acc[mi][6], acc[mi][7]);
    }
  }
  __syncthreads();
  if (wv_ >= 2) {
    float* rb = &red[(wv_ - 2) * 4096];
    #pragma unroll
    for (int mi = 0; mi < 8; ++mi) {
      float* q = &rb[((mg << 3) + mi) * 128 + (ng << 3)];
      float4 c0 = ld4(q), c1 = ld4(q + 4);
      *(float4*)q       = make_float4(c0.x+acc[mi][0], c0.y+acc[mi][1], c0.z+acc[mi][2], c0.w+acc[mi][3]);
      *(float4*)(q + 4) = make_float4(c1.x+acc[mi][4], c1.y+acc[mi][5], c1.z+acc[mi][6], c1.w+acc[mi][7]);
    }
  }
  __syncthreads();
  // partial write (coherent)
  for (int i = tid; i < 2048; i += NTHR) {
    float2 v = make_float2(red[2*i] + red[4096 + 2*i], red[2*i+1] + red[4096 + 2*i+1]);
    st2v(partSlab + 2 * i, v);
  }
}

DEV float2 redsumN(const float* part, int e0, int S) {
  float2 s = make_float2(0.f, 0.f);
  #pragma unroll 4
  for (int q = 0; q < S; ++q) {
    float2 v = ld2v(part + q * 4096 + e0);
    s.x += v.x; s.y += v.y;
  }
  return s;
}

// wait until all S producers of this tile have stored their partials (monotonic counter)
DEV void tile_wait(float* ws, int tcIdx, unsigned target) {
  __syncthreads();  // drains every wave's vmcnt (compiler emits s_waitcnt before s_barrier)
  if (threadIdx.x == 0) {
    asm volatile("s_waitcnt vmcnt(0)" ::: "memory");
    unsigned* c = (unsigned*)(ws + OFF_TC) + tcIdx * 16;
    __hip_atomic_fetch_add(c, 1u, __ATOMIC_RELAXED, __HIP_MEMORY_SCOPE_AGENT);
    while (__hip_atomic_load(c, __ATOMIC_RELAXED, __HIP_MEMORY_SCOPE_AGENT) < target)
      __builtin_amdgcn_s_sleep(1);
  }
  __syncthreads();
}

// fence-free 2-level grid barrier (relaxed fabric atomics, monotonic)
DEV void gbar(float* ws, int wg, unsigned tgt) {
  __syncthreads();
  if (threadIdx.x == 0) {
    asm volatile("s_waitcnt vmcnt(0)" ::: "memory");
    unsigned* base = (unsigned*)ws;
    unsigned* leaf = base + (wg >> 3) * 16;
    unsigned* root = base + 512;
    unsigned* gen  = base + 544;
    unsigned a = __hip_atomic_fetch_add(leaf, 1u, __ATOMIC_RELAXED, __HIP_MEMORY_SCOPE_AGENT);
    if ((a & 7u) == 7u) {
      unsigned r = __hip_atomic_fetch_add(root, 1u, __ATOMIC_RELAXED, __HIP_MEMORY_SCOPE_AGENT);
      if ((r & 31u) == 31u)
        __hip_atomic_store(gen, tgt, __ATOMIC_RELAXED, __HIP_MEMORY_SCOPE_AGENT);
    }
    while (__hip_atomic_load(gen, __ATOMIC_RELAXED, __HIP_MEMORY_SCOPE_AGENT) < tgt)
      __builtin_amdgcn_s_sleep(1);
  }
  __syncthreads();
}

__global__ void ggru_init(float* ws) {
  const int i = blockIdx.x * 256 + threadIdx.x;
  if (i < 2048) ws[i] = 0.f;                        // barrier + tile counters
  const int j = i - 2048;
  if (j >= 0 && j < Bb * Hd) ws[OFF_HB + j] = 0.f;  // H0 = 0 (buffer 0)
}

__global__ __launch_bounds__(NTHR)
void ggru_persist(P p) {
  extern __shared__ float sm[];
  const int wg = blockIdx.x, tid = threadIdx.x;
  float* ws = p.ws;
  unsigned bt = 0;

  // ---------- prologue: X-mix for step 1 (input row 0) ----------
  if (wg < 32) {
    const int ks = wg & 7, tile = wg >> 3;
    const int Mt = tile & 1, Nt = tile >> 1, n0 = Nt * 128;
    float* part = ws + OFF_PX + tile * (8 * 4096);
    gemm_job<JX, 64>(p, sm, 0, nullptr, 0, Mt * 32, n0, ks * 64,
                     p.fWxt, Ii, p.fWxm, Ii, Ii, part + ks * 4096);
    tile_wait(ws, 56 + tile, 8u);
    const int e0 = (ks * 256 + tid) * 2;
    float2 s = redsumN(part, e0, 8);
    const int c = e0 & 127, brow = Mt * 32 + (e0 >> 7), col = n0 + c;
    float2 bv = *(const float2*)&p.fxb[col];
    float xg0 = sig1(s.x + bv.x), xg1 = sig1(s.y + bv.y);
    float2 xt = *(const float2*)&p.tt[(brow * Tt + 0) * Ii + col];
    float2 xm = *(const float2*)&p.mark[(brow * Tt + 0) * Ii + col];
    st2v(ws + OFF_XB + 1 * Bb * Ii + brow * Ii + col,
         make_float2(xg0 * xt.x + (1.f - xg0) * xm.x, xg1 * xt.y + (1.f - xg1) * xm.y));
  }
  gbar(ws, wg, ++bt);

  for (int t = 1; t <= Tt; ++t) {
    // ---------- phase A: 4 gate pre-acts, σ'd -> G ----------
    {
      const int ks = wg & 7, tile = wg >> 3;           // 32 tiles × 8 k-slabs
      const int Mt = tile & 1, ntl = tile >> 1;
      const int gate = ntl >> 2, Nt = ntl & 3, n0 = Nt * 128;
      const float* wx = gate==0 ? p.Wxz_t : gate==1 ? p.Wxr_t : gate==2 ? p.Wxz_m : p.Wxr_m;
      const float* wh = gate==0 ? p.Whz_t : gate==1 ? p.Whr_t : gate==2 ? p.Whz_m : p.Whr_m;
      const float* xin = (gate < 2) ? p.tt : p.mark;
      float* part = ws + OFF_PA + tile * (8 * 4096);
      gemm_job<JA, 96>(p, sm, t, xin, 0, Mt * 32, n0, ks * 96,
                       wx, Hd, wh, Hd, Ii, part + ks * 4096);
      tile_wait(ws, tile, 8u * (unsigned)t);
      const int e0 = (ks * 256 + tid) * 2;
      float2 s = redsumN(part, e0, 8);
      const int c = e0 & 127, brow = Mt * 32 + (e0 >> 7), col = n0 + c;
      const float* bias = gate==0 ? p.bz_t : gate==1 ? p.br_t : gate==2 ? p.bz_m : p.br_m;
      float2 bv = *(const float2*)&bias[col];
      st2v(ws + OFF_G + gate * Bb * Hd + brow * Hd + col,
           make_float2(sig1(s.x + bv.x), sig1(s.y + bv.y)));
    }
    gbar(ws, wg, ++bt);
    // ---------- phase B: fused z/r, σ'd -> F ----------
    {
      const int ks = wg & 15, tile = wg >> 4;          // 16 tiles × 16 k-slabs
      const int Mt = tile & 1, ntl = tile >> 1;
      const int sd = ntl >> 2, Nt = ntl & 3, n0 = Nt * 128;
      const float* wa = sd ? p.fWrt : p.fWzt;
      const float* wb = sd ? p.fWrm : p.fWzm;
      float* part = ws + OFF_PB + tile * (16 * 4096);
      gemm_job<JB, 64>(p, sm, t, nullptr, sd, Mt * 32, n0, ks * 64,
                       wa, Hd, wb, Hd, Hd, part + ks * 4096);
      tile_wait(ws, 32 + tile, 16u * (unsigned)t);
      if (tid < 128) {
        const int e0 = (ks * 128 + tid) * 2;
        float2 s = redsumN(part, e0, 16);
        const int c = e0 & 127, brow = Mt * 32 + (e0 >> 7), col = n0 + c;
        const float* bias = sd ? p.frb : p.fzb;
        float2 bv = *(const float2*)&bias[col];
        st2v(ws + OFF_F + sd * Bb * Hd + brow * Hd + col,
             make_float2(sig1(s.x + bv.x), sig1(s.y + bv.y)));
      }
    }
    gbar(ws, wg, ++bt);
    // ---------- phase C: H̃ GEMM + H(t) materialize + out; X-mix(t+1) ----------
    if (wg < 64) {
      const int ks = wg & 7, tile = wg >> 3;           // 8 tiles × 8 k-slabs
      const int Mt = tile & 1, Nt = tile >> 1, n0 = Nt * 128;
      float* part = ws + OFF_PC + tile * (8 * 4096);
      gemm_job<JCH, 96>(p, sm, t, nullptr, 0, Mt * 32, n0, ks * 96,
                        p.Wxh, Hd, p.Whh, Hd, Ii, part + ks * 4096);
      tile_wait(ws, 48 + tile, 8u * (unsigned)t);
      const int e0 = (ks * 256 + tid) * 2;
      float2 s = redsumN(part, e0, 8);
      const int c = e0 & 127, brow = Mt * 32 + (e0 >> 7), col = n0 + c;
      float2 bv = *(const float2*)&p.bh[col];
      float ht0 = tanh1(s.x + bv.x), ht1 = tanh1(s.y + bv.y);
      const int base = brow * Hd + col;
      float2 zf = ld2v(ws + OFF_F + base);
      float2 zt = ld2v(ws + OFF_G + base);
      float2 zm = ld2v(ws + OFF_G + 2 * Bb * Hd + base);
      float2 ho = ld2v(ws + OFF_HB + ((t - 1) & 1) * Bb * Hd + base);
      float Z0 = zf.x * zt.x + (1.f - zf.x) * zm.x;
      float Z1 = zf.y * zt.y + (1.f - zf.y) * zm.y;
      float2 hn = make_float2(Z0 * ho.x + (1.f - Z0) * ht0, Z1 * ho.y + (1.f - Z1) * ht1);
      st2v(ws + OFF_HB + (t & 1) * Bb * Hd + base, hn);
      *(float2*)&p.out[(brow * Tt + (t - 1)) * Hd + col] = hn;
      if (t == Tt) *(float2*)&p.out[Bb * Tt * Hd + brow * Hd + col] = hn;
    } else if (wg < 96 && t < Tt) {
      const int w2 = wg - 64;
      const int ks = w2 & 7, tile = w2 >> 3;           // 4 tiles × 8 k-slabs
      const int Mt = tile & 1, Nt = tile >> 1, n0 = Nt * 128;
      float* part = ws + OFF_PX + tile * (8 * 4096);
      gemm_job<JX, 64>(p, sm, t, nullptr, 0, Mt * 32, n0, ks * 64,
                       p.fWxt, Ii, p.fWxm, Ii, Ii, part + ks * 4096);
      tile_wait(ws, 56 + tile, 8u * (unsigned)(t + 1));
      const int e0 = (ks * 256 + tid) * 2;
      float2 s = redsumN(part, e0, 8);
      const int c = e0 & 127, brow = Mt * 32 + (e0 >> 7), col = n0 + c;
      float2 bv = *(const float2*)&p.fxb[col];
      float xg0 = sig1(s.x + bv.x), xg1 = sig1(s.y + bv.y);
      float2 xt = *(const float2*)&p.tt[(brow * Tt + t) * Ii + col];
      float2 xm = *(const float2*)&p.mark[(brow * Tt + t) * Ii + col];
      st2v(ws + OFF_XB + ((t + 1) & 1) * Bb * Ii + brow * Ii + col,
           make_float2(xg0 * xt.x + (1.f - xg0) * xm.x, xg1 * xt.y + (1.f - xg1) * xm.y));
    }
    gbar(ws, wg, ++bt);
  }
}

extern "C" void kernel_launch(void* const* d_in, const int* in_sizes, int n_in,
                              void* d_out, int out_size, void* d_ws, size_t ws_size,
                              hipStream_t stream) {
  P pr;
  pr.tt    = (const float*)d_in[0];
  pr.mark  = (const float*)d_in[1];
  pr.Wxz_t = (const float*)d_in[2];
  pr.Wxr_t = (const float*)d_in[3];
  pr.Wxz_m = (const float*)d_in[4];
  pr.Wxr_m = (const float*)d_in[5];
  pr.Wxh   = (const float*)d_in[6];
  pr.Whz_t = (const float*)d_in[7];
  pr.Whr_t = (const float*)d_in[8];
  pr.Whz_m = (const float*)d_in[9];
  pr.Whr_m = (const float*)d_in[10];
  pr.Whh   = (const float*)d_in[11];
  pr.bz_t  = (const float*)d_in[12];
  pr.br_t  = (const float*)d_in[13];
  pr.bz_m  = (const float*)d_in[14];
  pr.br_m  = (const float*)d_in[15];
  pr.bh    = (const float*)d_in[16];
  pr.fWrt  = (const float*)d_in[17];
  pr.fWrm  = (const float*)d_in[18];
  pr.fWzt  = (const float*)d_in[19];
  pr.fWzm  = (const float*)d_in[20];
  pr.fWxt  = (const float*)d_in[21];
  pr.fWxm  = (const float*)d_in[22];
  pr.frb   = (const float*)d_in[23];
  pr.fzb   = (const float*)d_in[24];
  pr.fxb   = (const float*)d_in[25];
  pr.out = (float*)d_out;
  pr.ws  = (float*)d_ws;

  hipLaunchKernelGGL(ggru_init, dim3(136), dim3(256), 0, stream, (float*)d_ws);

  void* args[] = { (void*)&pr };
  hipError_t err = hipLaunchCooperativeKernel((const void*)ggru_persist,
                                              dim3(NWG), dim3(NTHR),
                                              args, (unsigned)SMEM_BYTES, stream);
  if (err != hipSuccess) {
    hipLaunchKernelGGL(ggru_persist, dim3(NWG), dim3(NTHR), SMEM_BYTES, stream, pr);
  }
}

// Round 4
// 18313.692 us; speedup vs baseline: 6.1427x; 1.0318x over previous
//
#include <hip/hip_runtime.h>

#define DEV __device__ __forceinline__

constexpr int Bb = 64, Tt = 512, Ii = 256, Hd = 512;
constexpr int NWG = 256, NTHR = 256;

// ---- workspace layout (floats) ----
// [0,1024): grid barrier (leaf[32] @ stride 16 uints, root @ uint 512, gen @ uint 544)
// [1024,2048): tile counters (60 × stride 16 uints): A:0-31 B:32-47 C:48-55 X:56-59
constexpr int OFF_TC = 1024;
constexpr int OFF_G  = 2048;                  // gates σ'd: [4][64][512] = 131072
constexpr int OFF_F  = OFF_G + 4 * Bb * Hd;   // F0 = z σ'd; F1 = R·H materialized
constexpr int OFF_HB = OFF_F + 2 * Bb * Hd;   // H double-buffer: [2][64][512]
constexpr int OFF_XB = OFF_HB + 2 * Bb * Hd;  // X-mixed double-buffer: [2][64][256]
constexpr int OFF_PA = OFF_XB + 2 * Bb * Ii;  // A partials: 32 tiles × 8 × 4096
constexpr int OFF_PB = OFF_PA + 32 * 8 * 4096;// B partials: 16 × 16 × 4096
constexpr int OFF_PC = OFF_PB + 16 * 16 * 4096;// C partials: 8 × 8 × 4096
constexpr int OFF_PX = OFF_PC + 8 * 8 * 4096; // X partials: 4 × 8 × 4096

#define SMEM_BYTES (96*36*4 + 96*128*4)       // ldsA[96][36] + ldsW[96][128] = 62976 B

struct P {
  const float *tt, *mark;
  const float *Wxz_t, *Wxr_t, *Wxz_m, *Wxr_m, *Wxh;
  const float *Whz_t, *Whr_t, *Whz_m, *Whr_m, *Whh;
  const float *bz_t, *br_t, *bz_m, *br_m, *bh;
  const float *fWrt, *fWrm, *fWzt, *fWzm, *fWxt, *fWxm;
  const float *frb, *fzb, *fxb;
  float* out; float* ws;
};

enum { JA = 0, JB = 1, JCH = 2, JX = 3 };

DEV float sig1(float x) { return 1.f / (1.f + __expf(-x)); }
DEV float tanh1(float x) { return 2.f * sig1(2.f * x) - 1.f; }
DEV float4 ld4(const float* p) { return *(const float4*)p; }

// coherent (agent-scope, L2-bypass) 8B load/store — no cache maintenance emitted
DEV float2 ld2v(const float* p) {
  unsigned long long u = __hip_atomic_load((const unsigned long long*)p,
                                           __ATOMIC_RELAXED, __HIP_MEMORY_SCOPE_AGENT);
  return __builtin_bit_cast(float2, u);
}
DEV void st2v(float* p, float2 v) {
  __hip_atomic_store((unsigned long long*)p, __builtin_bit_cast(unsigned long long, v),
                     __ATOMIC_RELAXED, __HIP_MEMORY_SCOPE_AGENT);
}
DEV float4 ld4v(const float* p) {
  float2 a = ld2v(p), b = ld2v(p + 2);
  return make_float4(a.x, a.y, b.x, b.y);
}

// A-operand generator for 4 consecutive k (k%4==0; 4-groups never straddle segment bounds)
template<int TYPE>
DEV float4 loadA4(const P& p, int t, const float* aux, int side, int b, int k) {
  const float* ws = p.ws;
  if constexpr (TYPE == JA) {          // [X_raw(256) | H(t-1)(512)]
    if (k < Ii) return ld4(&aux[(b * Tt + (t - 1)) * Ii + k]);
    return ld4v(ws + OFF_HB + ((t - 1) & 1) * Bb * Hd + b * Hd + (k - Ii));
  } else if constexpr (TYPE == JB) {   // [Zt|Zm] (side0) or [Rt|Rm] (side1), σ'd finals
    const int g = (k < Hd) ? side : side + 2;
    const int j = (k < Hd) ? k : k - Hd;
    return ld4v(ws + OFF_G + g * Bb * Hd + b * Hd + j);
  } else if constexpr (TYPE == JCH) {  // [X_mixed(256) | R·H(512)]  (R·H precomputed in phase B)
    if (k < Ii) return ld4v(ws + OFF_XB + (t & 1) * Bb * Ii + b * Ii + k);
    return ld4v(ws + OFF_F + Bb * Hd + b * Hd + (k - Ii));
  } else {                             // JX: [Xt_raw | Xm_raw], input row t (for step t+1)
    if (k < Ii) return ld4(&p.tt[(b * Tt + t) * Ii + k]);
    return ld4(&p.mark[(b * Tt + t) * Ii + (k - Ii)]);
  }
}

// GEMM job: output tile [32 x 128], K-chunk [K0,K0+KC). 4 waves split KC; 8x8/lane;
// LDS tree reduce; partial tile -> partSlab (coherent stores).
template<int TYPE, int KC>
DEV void gemm_job(const P& p, float* sm, int t, const float* aux, int side,
                  int brow0, int n0, int K0,
                  const float* wA, int sA, const float* wB, int sB, int kSpl,
                  float* partSlab) {
  float* ldsA = sm;             // [KC][36]
  float* ldsW = sm + 96 * 36;   // [KC][128]
  const int tid = threadIdx.x;
  constexpr int kq = KC >> 2;
  // stage A
  for (int idx = tid; idx < (kq << 5); idx += NTHR) {
    const int m = idx / kq, k4 = idx - m * kq;
    const int k = K0 + (k4 << 2);
    float4 av = loadA4<TYPE>(p, t, aux, side, brow0 + m, k);
    float* d = &ldsA[(k4 << 2) * 36 + m];
    d[0] = av.x; d[36] = av.y; d[72] = av.z; d[108] = av.w;
  }
  // stage W (plain cached loads; weights stay per-XCD L2-resident)
  for (int idx = tid; idx < (KC << 5); idx += NTHR) {
    const int kk = idx >> 5, nj = (idx & 31) << 2;
    const int k = K0 + kk, n = n0 + nj;
    float4 wv = (k < kSpl) ? ld4(&wA[k * sA + n]) : ld4(&wB[(k - kSpl) * sB + n]);
    *(float4*)&ldsW[(kk << 7) + nj] = wv;
  }
  __syncthreads();
  // k-loop: 8x8 per lane
  const int wv_ = tid >> 6, lane = tid & 63, mg = lane >> 4, ng = lane & 15;
  float acc[8][8];
  #pragma unroll
  for (int i = 0; i < 8; ++i)
    #pragma unroll
    for (int j = 0; j < 8; ++j) acc[i][j] = 0.f;
  constexpr int kcw = KC >> 2;
  for (int kk = wv_ * kcw, ke = (wv_ + 1) * kcw; kk < ke; ++kk) {
    float4 a0 = ld4(&ldsA[kk * 36 + (mg << 3)]);
    float4 a1 = ld4(&ldsA[kk * 36 + (mg << 3) + 4]);
    float4 w0 = ld4(&ldsW[(kk << 7) + (ng << 3)]);
    float4 w1 = ld4(&ldsW[(kk << 7) + (ng << 3) + 4]);
    const float am[8] = {a0.x,a0.y,a0.z,a0.w,a1.x,a1.y,a1.z,a1.w};
    const float wn[8] = {w0.x,w0.y,w0.z,w0.w,w1.x,w1.y,w1.z,w1.w};
    #pragma unroll
    for (int mi = 0; mi < 8; ++mi)
      #pragma unroll
      for (int ni = 0; ni < 8; ++ni)
        acc[mi][ni] = fmaf(am[mi], wn[ni], acc[mi][ni]);
  }
  __syncthreads();
  // 4-wave LDS reduce: red[2][4096] aliases staging LDS
  float* red = sm;
  if (wv_ < 2) {
    float* rb = &red[wv_ * 4096];
    #pragma unroll
    for (int mi = 0; mi < 8; ++mi) {
      float* q = &rb[((mg << 3) + mi) * 128 + (ng << 3)];
      *(float4*)q       = make_float4(acc[mi][0], acc[mi][1], acc[mi][2], acc[mi][3]);
      *(float4*)(q + 4) = make_float4(acc[mi][4], acc[mi][5], acc[mi][6], acc[mi][7]);
    }
  }
  __syncthreads();
  if (wv_ >= 2) {
    float* rb = &red[(wv_ - 2) * 4096];
    #pragma unroll
    for (int mi = 0; mi < 8; ++mi) {
      float* q = &rb[((mg << 3) + mi) * 128 + (ng << 3)];
      float4 c0 = ld4(q), c1 = ld4(q + 4);
      *(float4*)q       = make_float4(c0.x+acc[mi][0], c0.y+acc[mi][1], c0.z+acc[mi][2], c0.w+acc[mi][3]);
      *(float4*)(q + 4) = make_float4(c1.x+acc[mi][4], c1.y+acc[mi][5], c1.z+acc[mi][6], c1.w+acc[mi][7]);
    }
  }
  __syncthreads();
  // partial write (coherent)
  for (int i = tid; i < 2048; i += NTHR) {
    float2 v = make_float2(red[2*i] + red[4096 + 2*i], red[2*i+1] + red[4096 + 2*i+1]);
    st2v(partSlab + 2 * i, v);
  }
}

DEV float2 redsumN(const float* part, int e0, int S) {
  float2 s = make_float2(0.f, 0.f);
  #pragma unroll 4
  for (int q = 0; q < S; ++q) {
    float2 v = ld2v(part + q * 4096 + e0);
    s.x += v.x; s.y += v.y;
  }
  return s;
}

// wait until all S producers of this tile have stored their partials (monotonic counter)
DEV void tile_wait(float* ws, int tcIdx, unsigned target) {
  __syncthreads();  // drains every wave's vmcnt (compiler emits s_waitcnt before s_barrier)
  if (threadIdx.x == 0) {
    asm volatile("s_waitcnt vmcnt(0)" ::: "memory");
    unsigned* c = (unsigned*)(ws + OFF_TC) + tcIdx * 16;
    __hip_atomic_fetch_add(c, 1u, __ATOMIC_RELAXED, __HIP_MEMORY_SCOPE_AGENT);
    while (__hip_atomic_load(c, __ATOMIC_RELAXED, __HIP_MEMORY_SCOPE_AGENT) < target)
      __builtin_amdgcn_s_sleep(1);
  }
  __syncthreads();
}

// fence-free 2-level grid barrier (relaxed fabric atomics, monotonic)
DEV void gbar(float* ws, int wg, unsigned tgt) {
  __syncthreads();
  if (threadIdx.x == 0) {
    asm volatile("s_waitcnt vmcnt(0)" ::: "memory");
    unsigned* base = (unsigned*)ws;
    unsigned* leaf = base + (wg >> 3) * 16;
    unsigned* root = base + 512;
    unsigned* gen  = base + 544;
    unsigned a = __hip_atomic_fetch_add(leaf, 1u, __ATOMIC_RELAXED, __HIP_MEMORY_SCOPE_AGENT);
    if ((a & 7u) == 7u) {
      unsigned r = __hip_atomic_fetch_add(root, 1u, __ATOMIC_RELAXED, __HIP_MEMORY_SCOPE_AGENT);
      if ((r & 31u) == 31u)
        __hip_atomic_store(gen, tgt, __ATOMIC_RELAXED, __HIP_MEMORY_SCOPE_AGENT);
    }
    while (__hip_atomic_load(gen, __ATOMIC_RELAXED, __HIP_MEMORY_SCOPE_AGENT) < tgt)
      __builtin_amdgcn_s_sleep(1);
  }
  __syncthreads();
}

__global__ void ggru_init(float* ws) {
  const int i = blockIdx.x * 256 + threadIdx.x;
  if (i < 2048) ws[i] = 0.f;                        // barrier + tile counters
  const int j = i - 2048;
  if (j >= 0 && j < Bb * Hd) ws[OFF_HB + j] = 0.f;  // H0 = 0 (buffer 0)
}

__global__ __launch_bounds__(NTHR)
void ggru_persist(P p) {
  extern __shared__ float sm[];
  const int wg = blockIdx.x, tid = threadIdx.x;
  float* ws = p.ws;
  unsigned bt = 0;

  // ---------- prologue: X-mix for step 1 (input row 0) ----------
  if (wg < 32) {
    const int ks = wg & 7, tile = wg >> 3;
    const int Mt = tile & 1, Nt = tile >> 1, n0 = Nt * 128;
    float* part = ws + OFF_PX + tile * (8 * 4096);
    gemm_job<JX, 64>(p, sm, 0, nullptr, 0, Mt * 32, n0, ks * 64,
                     p.fWxt, Ii, p.fWxm, Ii, Ii, part + ks * 4096);
    tile_wait(ws, 56 + tile, 8u);
    const int e0 = (ks * 256 + tid) * 2;
    float2 s = redsumN(part, e0, 8);
    const int c = e0 & 127, brow = Mt * 32 + (e0 >> 7), col = n0 + c;
    float2 bv = *(const float2*)&p.fxb[col];
    float xg0 = sig1(s.x + bv.x), xg1 = sig1(s.y + bv.y);
    float2 xt = *(const float2*)&p.tt[(brow * Tt + 0) * Ii + col];
    float2 xm = *(const float2*)&p.mark[(brow * Tt + 0) * Ii + col];
    st2v(ws + OFF_XB + 1 * Bb * Ii + brow * Ii + col,
         make_float2(xg0 * xt.x + (1.f - xg0) * xm.x, xg1 * xt.y + (1.f - xg1) * xm.y));
  }
  gbar(ws, wg, ++bt);

  for (int t = 1; t <= Tt; ++t) {
    // ---------- phase A: 4 gate pre-acts, σ'd -> G ----------
    {
      const int ks = wg & 7, tile = wg >> 3;           // 32 tiles × 8 k-slabs
      const int Mt = tile & 1, ntl = tile >> 1;
      const int gate = ntl >> 2, Nt = ntl & 3, n0 = Nt * 128;
      const float* wx = gate==0 ? p.Wxz_t : gate==1 ? p.Wxr_t : gate==2 ? p.Wxz_m : p.Wxr_m;
      const float* wh = gate==0 ? p.Whz_t : gate==1 ? p.Whr_t : gate==2 ? p.Whz_m : p.Whr_m;
      const float* xin = (gate < 2) ? p.tt : p.mark;
      float* part = ws + OFF_PA + tile * (8 * 4096);
      gemm_job<JA, 96>(p, sm, t, xin, 0, Mt * 32, n0, ks * 96,
                       wx, Hd, wh, Hd, Ii, part + ks * 4096);
      tile_wait(ws, tile, 8u * (unsigned)t);
      const int e0 = (ks * 256 + tid) * 2;
      float2 s = redsumN(part, e0, 8);
      const int c = e0 & 127, brow = Mt * 32 + (e0 >> 7), col = n0 + c;
      const float* bias = gate==0 ? p.bz_t : gate==1 ? p.br_t : gate==2 ? p.bz_m : p.br_m;
      float2 bv = *(const float2*)&bias[col];
      st2v(ws + OFF_G + gate * Bb * Hd + brow * Hd + col,
           make_float2(sig1(s.x + bv.x), sig1(s.y + bv.y)));
    }
    gbar(ws, wg, ++bt);
    // ---------- phase B: fused z/r (K=1024); r-side reducers also materialize R·H ----------
    {
      const int ks = wg & 15, tile = wg >> 4;          // 16 tiles × 16 k-slabs
      const int Mt = tile & 1, ntl = tile >> 1;
      const int sd = ntl >> 2, Nt = ntl & 3, n0 = Nt * 128;
      const float* wa = sd ? p.fWrt : p.fWzt;
      const float* wb = sd ? p.fWrm : p.fWzm;
      float* part = ws + OFF_PB + tile * (16 * 4096);
      gemm_job<JB, 64>(p, sm, t, nullptr, sd, Mt * 32, n0, ks * 64,
                       wa, Hd, wb, Hd, Hd, part + ks * 4096);
      tile_wait(ws, 32 + tile, 16u * (unsigned)t);
      if (tid < 128) {
        const int e0 = (ks * 128 + tid) * 2;
        float2 s = redsumN(part, e0, 16);
        const int c = e0 & 127, brow = Mt * 32 + (e0 >> 7), col = n0 + c;
        const int base = brow * Hd + col;
        const float* bias = sd ? p.frb : p.fzb;
        float2 bv = *(const float2*)&bias[col];
        float2 g = make_float2(sig1(s.x + bv.x), sig1(s.y + bv.y));
        if (sd == 0) {
          st2v(ws + OFF_F + base, g);                  // z
        } else {                                       // r -> R·H = (r*Rt+(1-r)*Rm)*H(t-1)
          float2 rt = ld2v(ws + OFF_G + 1 * Bb * Hd + base);
          float2 rm = ld2v(ws + OFF_G + 3 * Bb * Hd + base);
          float2 ho = ld2v(ws + OFF_HB + ((t - 1) & 1) * Bb * Hd + base);
          st2v(ws + OFF_F + Bb * Hd + base,
               make_float2((g.x * rt.x + (1.f - g.x) * rm.x) * ho.x,
                           (g.y * rt.y + (1.f - g.y) * rm.y) * ho.y));
        }
      }
    }
    gbar(ws, wg, ++bt);
    // ---------- phase C: H̃ GEMM + H(t) materialize + out; X-mix(t+1) ----------
    if (wg < 64) {
      const int ks = wg & 7, tile = wg >> 3;           // 8 tiles × 8 k-slabs
      const int Mt = tile & 1, Nt = tile >> 1, n0 = Nt * 128;
      float* part = ws + OFF_PC + tile * (8 * 4096);
      gemm_job<JCH, 96>(p, sm, t, nullptr, 0, Mt * 32, n0, ks * 96,
                        p.Wxh, Hd, p.Whh, Hd, Ii, part + ks * 4096);
      tile_wait(ws, 48 + tile, 8u * (unsigned)t);
      const int e0 = (ks * 256 + tid) * 2;
      float2 s = redsumN(part, e0, 8);
      const int c = e0 & 127, brow = Mt * 32 + (e0 >> 7), col = n0 + c;
      float2 bv = *(const float2*)&p.bh[col];
      float ht0 = tanh1(s.x + bv.x), ht1 = tanh1(s.y + bv.y);
      const int base = brow * Hd + col;
      float2 zf = ld2v(ws + OFF_F + base);
      float2 zt = ld2v(ws + OFF_G + base);
      float2 zm = ld2v(ws + OFF_G + 2 * Bb * Hd + base);
      float2 ho = ld2v(ws + OFF_HB + ((t - 1) & 1) * Bb * Hd + base);
      float Z0 = zf.x * zt.x + (1.f - zf.x) * zm.x;
      float Z1 = zf.y * zt.y + (1.f - zf.y) * zm.y;
      float2 hn = make_float2(Z0 * ho.x + (1.f - Z0) * ht0, Z1 * ho.y + (1.f - Z1) * ht1);
      st2v(ws + OFF_HB + (t & 1) * Bb * Hd + base, hn);
      *(float2*)&p.out[(brow * Tt + (t - 1)) * Hd + col] = hn;
      if (t == Tt) *(float2*)&p.out[Bb * Tt * Hd + brow * Hd + col] = hn;
    } else if (wg < 96 && t < Tt) {
      const int w2 = wg - 64;
      const int ks = w2 & 7, tile = w2 >> 3;           // 4 tiles × 8 k-slabs
      const int Mt = tile & 1, Nt = tile >> 1, n0 = Nt * 128;
      float* part = ws + OFF_PX + tile * (8 * 4096);
      gemm_job<JX, 64>(p, sm, t, nullptr, 0, Mt * 32, n0, ks * 64,
                       p.fWxt, Ii, p.fWxm, Ii, Ii, part + ks * 4096);
      tile_wait(ws, 56 + tile, 8u * (unsigned)(t + 1));
      const int e0 = (ks * 256 + tid) * 2;
      float2 s = redsumN(part, e0, 8);
      const int c = e0 & 127, brow = Mt * 32 + (e0 >> 7), col = n0 + c;
      float2 bv = *(const float2*)&p.fxb[col];
      float xg0 = sig1(s.x + bv.x), xg1 = sig1(s.y + bv.y);
      float2 xt = *(const float2*)&p.tt[(brow * Tt + t) * Ii + col];
      float2 xm = *(const float2*)&p.mark[(brow * Tt + t) * Ii + col];
      st2v(ws + OFF_XB + ((t + 1) & 1) * Bb * Ii + brow * Ii + col,
           make_float2(xg0 * xt.x + (1.f - xg0) * xm.x, xg1 * xt.y + (1.f - xg1) * xm.y));
    }
    gbar(ws, wg, ++bt);
  }
}

extern "C" void kernel_launch(void* const* d_in, const int* in_sizes, int n_in,
                              void* d_out, int out_size, void* d_ws, size_t ws_size,
                              hipStream_t stream) {
  P pr;
  pr.tt    = (const float*)d_in[0];
  pr.mark  = (const float*)d_in[1];
  pr.Wxz_t = (const float*)d_in[2];
  pr.Wxr_t = (const float*)d_in[3];
  pr.Wxz_m = (const float*)d_in[4];
  pr.Wxr_m = (const float*)d_in[5];
  pr.Wxh   = (const float*)d_in[6];
  pr.Whz_t = (const float*)d_in[7];
  pr.Whr_t = (const float*)d_in[8];
  pr.Whz_m = (const float*)d_in[9];
  pr.Whr_m = (const float*)d_in[10];
  pr.Whh   = (const float*)d_in[11];
  pr.bz_t  = (const float*)d_in[12];
  pr.br_t  = (const float*)d_in[13];
  pr.bz_m  = (const float*)d_in[14];
  pr.br_m  = (const float*)d_in[15];
  pr.bh    = (const float*)d_in[16];
  pr.fWrt  = (const float*)d_in[17];
  pr.fWrm  = (const float*)d_in[18];
  pr.fWzt  = (const float*)d_in[19];
  pr.fWzm  = (const float*)d_in[20];
  pr.fWxt  = (const float*)d_in[21];
  pr.fWxm  = (const float*)d_in[22];
  pr.frb   = (const float*)d_in[23];
  pr.fzb   = (const float*)d_in[24];
  pr.fxb   = (const float*)d_in[25];
  pr.out = (float*)d_out;
  pr.ws  = (float*)d_ws;

  hipLaunchKernelGGL(ggru_init, dim3(136), dim3(256), 0, stream, (float*)d_ws);

  void* args[] = { (void*)&pr };
  hipError_t err = hipLaunchCooperativeKernel((const void*)ggru_persist,
                                              dim3(NWG), dim3(NTHR),
                                              args, (unsigned)SMEM_BYTES, stream);
  if (err != hipSuccess) {
    hipLaunchKernelGGL(ggru_persist, dim3(NWG), dim3(NTHR), SMEM_BYTES, stream, pr);
  }
}

// Round 5
// 18024.905 us; speedup vs baseline: 6.2411x; 1.0160x over previous
//
#include <hip/hip_runtime.h>

#define DEV __device__ __forceinline__

constexpr int Bb = 64, Tt = 512, Ii = 256, Hd = 512;
constexpr int NWG = 256, NTHR = 256;

// ---- workspace layout (floats) ----
// uints [0,1024): leaf arrival counters, 32 leaves @ stride 32 uints (128B)
// uint  2048: root counter
// uints [4096,5120): per-leaf gen flags, 32 @ stride 32 uints (128B)
// uints [8192,10112): tile counters, 60 @ stride 32 uints: A:0-31 B:32-47 C:48-55 X:56-59
constexpr int OFF_G  = 16384;                 // gates σ'd: [4][64][512] = 131072
constexpr int OFF_F  = OFF_G + 4 * Bb * Hd;   // F0 = z σ'd; F1 = R·H materialized
constexpr int OFF_HB = OFF_F + 2 * Bb * Hd;   // H double-buffer: [2][64][512]
constexpr int OFF_XB = OFF_HB + 2 * Bb * Hd;  // X-mixed double-buffer: [2][64][256]
constexpr int OFF_PA = OFF_XB + 2 * Bb * Ii;  // A partials: 32 tiles × 8 × 4096
constexpr int OFF_PB = OFF_PA + 32 * 8 * 4096;// B partials: 16 × 16 × 4096
constexpr int OFF_PC = OFF_PB + 16 * 16 * 4096;// C partials: 8 × 8 × 4096
constexpr int OFF_PX = OFF_PC + 8 * 8 * 4096; // X partials: 4 × 8 × 4096
// end = 2801664 floats = 11.21 MB (< round-1's proven 12.19 MB)

#define SMEM_BYTES (96*36*4 + 96*128*4)       // ldsA[96][36] + ldsW[96][128] = 62976 B

struct P {
  const float *tt, *mark;
  const float *Wxz_t, *Wxr_t, *Wxz_m, *Wxr_m, *Wxh;
  const float *Whz_t, *Whr_t, *Whz_m, *Whr_m, *Whh;
  const float *bz_t, *br_t, *bz_m, *br_m, *bh;
  const float *fWrt, *fWrm, *fWzt, *fWzm, *fWxt, *fWxm;
  const float *frb, *fzb, *fxb;
  float* out; float* ws;
};

enum { JA = 0, JB = 1, JCH = 2, JX = 3 };

DEV float sig1(float x) { return 1.f / (1.f + __expf(-x)); }
DEV float tanh1(float x) { return 2.f * sig1(2.f * x) - 1.f; }
DEV float4 ld4(const float* p) { return *(const float4*)p; }

// coherent (agent-scope) 8B load/store — no cache maintenance emitted
DEV float2 ld2v(const float* p) {
  unsigned long long u = __hip_atomic_load((const unsigned long long*)p,
                                           __ATOMIC_RELAXED, __HIP_MEMORY_SCOPE_AGENT);
  return __builtin_bit_cast(float2, u);
}
DEV void st2v(float* p, float2 v) {
  __hip_atomic_store((unsigned long long*)p, __builtin_bit_cast(unsigned long long, v),
                     __ATOMIC_RELAXED, __HIP_MEMORY_SCOPE_AGENT);
}
DEV float4 ld4v(const float* p) {
  float2 a = ld2v(p), b = ld2v(p + 2);
  return make_float4(a.x, a.y, b.x, b.y);
}

// A-operand generator for 4 consecutive k (k%4==0; 4-groups never straddle segment bounds)
template<int TYPE>
DEV float4 loadA4(const P& p, int t, const float* aux, int side, int b, int k) {
  const float* ws = p.ws;
  if constexpr (TYPE == JA) {          // [X_raw(256) | H(t-1)(512)]
    if (k < Ii) return ld4(&aux[(b * Tt + (t - 1)) * Ii + k]);
    return ld4v(ws + OFF_HB + ((t - 1) & 1) * Bb * Hd + b * Hd + (k - Ii));
  } else if constexpr (TYPE == JB) {   // [Zt|Zm] (side0) or [Rt|Rm] (side1), σ'd finals
    const int g = (k < Hd) ? side : side + 2;
    const int j = (k < Hd) ? k : k - Hd;
    return ld4v(ws + OFF_G + g * Bb * Hd + b * Hd + j);
  } else if constexpr (TYPE == JCH) {  // [X_mixed(256) | R·H(512)]  (R·H precomputed in phase B)
    if (k < Ii) return ld4v(ws + OFF_XB + (t & 1) * Bb * Ii + b * Ii + k);
    return ld4v(ws + OFF_F + Bb * Hd + b * Hd + (k - Ii));
  } else {                             // JX: [Xt_raw | Xm_raw], input row t (for step t+1)
    if (k < Ii) return ld4(&p.tt[(b * Tt + t) * Ii + k]);
    return ld4(&p.mark[(b * Tt + t) * Ii + (k - Ii)]);
  }
}

// GEMM job: output tile [32 x 128], K-chunk [K0,K0+KC). 4 waves split KC; 8x8/lane;
// LDS tree reduce; partial tile -> partSlab (coherent stores).
template<int TYPE, int KC>
DEV void gemm_job(const P& p, float* sm, int t, const float* aux, int side,
                  int brow0, int n0, int K0,
                  const float* wA, int sA, const float* wB, int sB, int kSpl,
                  float* partSlab) {
  float* ldsA = sm;             // [KC][36]
  float* ldsW = sm + 96 * 36;   // [KC][128]
  const int tid = threadIdx.x;
  constexpr int kq = KC >> 2;
  // stage A
  for (int idx = tid; idx < (kq << 5); idx += NTHR) {
    const int m = idx / kq, k4 = idx - m * kq;
    const int k = K0 + (k4 << 2);
    float4 av = loadA4<TYPE>(p, t, aux, side, brow0 + m, k);
    float* d = &ldsA[(k4 << 2) * 36 + m];
    d[0] = av.x; d[36] = av.y; d[72] = av.z; d[108] = av.w;
  }
  // stage W (plain cached loads; weights stay per-XCD L2-resident)
  for (int idx = tid; idx < (KC << 5); idx += NTHR) {
    const int kk = idx >> 5, nj = (idx & 31) << 2;
    const int k = K0 + kk, n = n0 + nj;
    float4 wv = (k < kSpl) ? ld4(&wA[k * sA + n]) : ld4(&wB[(k - kSpl) * sB + n]);
    *(float4*)&ldsW[(kk << 7) + nj] = wv;
  }
  __syncthreads();
  // k-loop: 8x8 per lane
  const int wv_ = tid >> 6, lane = tid & 63, mg = lane >> 4, ng = lane & 15;
  float acc[8][8];
  #pragma unroll
  for (int i = 0; i < 8; ++i)
    #pragma unroll
    for (int j = 0; j < 8; ++j) acc[i][j] = 0.f;
  constexpr int kcw = KC >> 2;
  for (int kk = wv_ * kcw, ke = (wv_ + 1) * kcw; kk < ke; ++kk) {
    float4 a0 = ld4(&ldsA[kk * 36 + (mg << 3)]);
    float4 a1 = ld4(&ldsA[kk * 36 + (mg << 3) + 4]);
    float4 w0 = ld4(&ldsW[(kk << 7) + (ng << 3)]);
    float4 w1 = ld4(&ldsW[(kk << 7) + (ng << 3) + 4]);
    const float am[8] = {a0.x,a0.y,a0.z,a0.w,a1.x,a1.y,a1.z,a1.w};
    const float wn[8] = {w0.x,w0.y,w0.z,w0.w,w1.x,w1.y,w1.z,w1.w};
    #pragma unroll
    for (int mi = 0; mi < 8; ++mi)
      #pragma unroll
      for (int ni = 0; ni < 8; ++ni)
        acc[mi][ni] = fmaf(am[mi], wn[ni], acc[mi][ni]);
  }
  __syncthreads();
  // 4-wave LDS reduce: red[2][4096] aliases staging LDS
  float* red = sm;
  if (wv_ < 2) {
    float* rb = &red[wv_ * 4096];
    #pragma unroll
    for (int mi = 0; mi < 8; ++mi) {
      float* q = &rb[((mg << 3) + mi) * 128 + (ng << 3)];
      *(float4*)q       = make_float4(acc[mi][0], acc[mi][1], acc[mi][2], acc[mi][3]);
      *(float4*)(q + 4) = make_float4(acc[mi][4], acc[mi][5], acc[mi][6], acc[mi][7]);
    }
  }
  __syncthreads();
  if (wv_ >= 2) {
    float* rb = &red[(wv_ - 2) * 4096];
    #pragma unroll
    for (int mi = 0; mi < 8; ++mi) {
      float* q = &rb[((mg << 3) + mi) * 128 + (ng << 3)];
      float4 c0 = ld4(q), c1 = ld4(q + 4);
      *(float4*)q       = make_float4(c0.x+acc[mi][0], c0.y+acc[mi][1], c0.z+acc[mi][2], c0.w+acc[mi][3]);
      *(float4*)(q + 4) = make_float4(c1.x+acc[mi][4], c1.y+acc[mi][5], c1.z+acc[mi][6], c1.w+acc[mi][7]);
    }
  }
  __syncthreads();
  // partial write (coherent)
  for (int i = tid; i < 2048; i += NTHR) {
    float2 v = make_float2(red[2*i] + red[4096 + 2*i], red[2*i+1] + red[4096 + 2*i+1]);
    st2v(partSlab + 2 * i, v);
  }
}

DEV float2 redsumN(const float* part, int e0, int S) {
  float2 s = make_float2(0.f, 0.f);
  #pragma unroll 4
  for (int q = 0; q < S; ++q) {
    float2 v = ld2v(part + q * 4096 + e0);
    s.x += v.x; s.y += v.y;
  }
  return s;
}

// wait until all S producers of this tile have stored their partials (monotonic counter)
DEV void tile_wait(float* ws, int tcIdx, unsigned target) {
  __syncthreads();  // drains every wave's vmcnt (compiler emits s_waitcnt before s_barrier)
  if (threadIdx.x == 0) {
    asm volatile("s_waitcnt vmcnt(0)" ::: "memory");
    unsigned* c = (unsigned*)ws + 8192 + tcIdx * 32;   // 128B stride: 1 counter per line
    __hip_atomic_fetch_add(c, 1u, __ATOMIC_RELAXED, __HIP_MEMORY_SCOPE_AGENT);
    while (__hip_atomic_load(c, __ATOMIC_RELAXED, __HIP_MEMORY_SCOPE_AGENT) < target)
      __builtin_amdgcn_s_sleep(1);
  }
  __syncthreads();
}

// fence-free 2-level grid barrier; broadcast decontended via per-leaf gen flags
DEV void gbar(float* ws, int wg, unsigned tgt) {
  __syncthreads();
  if (threadIdx.x == 0) {
    asm volatile("s_waitcnt vmcnt(0)" ::: "memory");
    unsigned* base = (unsigned*)ws;
    unsigned* leaf = base + (wg >> 3) * 32;            // arrival, 128B stride
    unsigned* root = base + 2048;
    unsigned* lgen = base + 4096 + (wg >> 3) * 32;     // my leaf's gen flag
    unsigned a = __hip_atomic_fetch_add(leaf, 1u, __ATOMIC_RELAXED, __HIP_MEMORY_SCOPE_AGENT);
    if ((a & 7u) == 7u) {
      unsigned r = __hip_atomic_fetch_add(root, 1u, __ATOMIC_RELAXED, __HIP_MEMORY_SCOPE_AGENT);
      if ((r & 31u) == 31u) {
        #pragma unroll 4
        for (int i = 0; i < 32; ++i)
          __hip_atomic_store(base + 4096 + i * 32, tgt, __ATOMIC_RELAXED, __HIP_MEMORY_SCOPE_AGENT);
      }
    }
    while (__hip_atomic_load(lgen, __ATOMIC_RELAXED, __HIP_MEMORY_SCOPE_AGENT) < tgt)
      __builtin_amdgcn_s_sleep(1);
  }
  __syncthreads();
}

__global__ void ggru_init(float* ws) {
  const int i = blockIdx.x * 256 + threadIdx.x;
  if (i < 16384) ws[i] = 0.f;                       // barrier + gen flags + tile counters
  const int j = i - 16384;
  if (j >= 0 && j < Bb * Hd) ws[OFF_HB + j] = 0.f;  // H0 = 0 (buffer 0)
}

__global__ __launch_bounds__(NTHR)
void ggru_persist(P p) {
  extern __shared__ float sm[];
  const int wg = blockIdx.x, tid = threadIdx.x;
  float* ws = p.ws;
  unsigned bt = 0;

  // ---------- prologue: X-mix for step 1 (input row 0) ----------
  if (wg < 32) {
    const int ks = wg & 7, tile = wg >> 3;
    const int Mt = tile & 1, Nt = tile >> 1, n0 = Nt * 128;
    float* part = ws + OFF_PX + tile * (8 * 4096);
    gemm_job<JX, 64>(p, sm, 0, nullptr, 0, Mt * 32, n0, ks * 64,
                     p.fWxt, Ii, p.fWxm, Ii, Ii, part + ks * 4096);
    tile_wait(ws, 56 + tile, 8u);
    const int e0 = (ks * 256 + tid) * 2;
    float2 s = redsumN(part, e0, 8);
    const int c = e0 & 127, brow = Mt * 32 + (e0 >> 7), col = n0 + c;
    float2 bv = *(const float2*)&p.fxb[col];
    float xg0 = sig1(s.x + bv.x), xg1 = sig1(s.y + bv.y);
    float2 xt = *(const float2*)&p.tt[(brow * Tt + 0) * Ii + col];
    float2 xm = *(const float2*)&p.mark[(brow * Tt + 0) * Ii + col];
    st2v(ws + OFF_XB + 1 * Bb * Ii + brow * Ii + col,
         make_float2(xg0 * xt.x + (1.f - xg0) * xm.x, xg1 * xt.y + (1.f - xg1) * xm.y));
  }
  gbar(ws, wg, ++bt);

  for (int t = 1; t <= Tt; ++t) {
    // ---------- phase A: 4 gate pre-acts, σ'd -> G ----------
    {
      const int ks = wg & 7, tile = wg >> 3;           // 32 tiles × 8 k-slabs
      const int Mt = tile & 1, ntl = tile >> 1;
      const int gate = ntl >> 2, Nt = ntl & 3, n0 = Nt * 128;
      const float* wx = gate==0 ? p.Wxz_t : gate==1 ? p.Wxr_t : gate==2 ? p.Wxz_m : p.Wxr_m;
      const float* wh = gate==0 ? p.Whz_t : gate==1 ? p.Whr_t : gate==2 ? p.Whz_m : p.Whr_m;
      const float* xin = (gate < 2) ? p.tt : p.mark;
      float* part = ws + OFF_PA + tile * (8 * 4096);
      gemm_job<JA, 96>(p, sm, t, xin, 0, Mt * 32, n0, ks * 96,
                       wx, Hd, wh, Hd, Ii, part + ks * 4096);
      tile_wait(ws, tile, 8u * (unsigned)t);
      const int e0 = (ks * 256 + tid) * 2;
      float2 s = redsumN(part, e0, 8);
      const int c = e0 & 127, brow = Mt * 32 + (e0 >> 7), col = n0 + c;
      const float* bias = gate==0 ? p.bz_t : gate==1 ? p.br_t : gate==2 ? p.bz_m : p.br_m;
      float2 bv = *(const float2*)&bias[col];
      st2v(ws + OFF_G + gate * Bb * Hd + brow * Hd + col,
           make_float2(sig1(s.x + bv.x), sig1(s.y + bv.y)));
    }
    gbar(ws, wg, ++bt);
    // ---------- phase B: fused z/r (K=1024); r-side reducers also materialize R·H ----------
    {
      const int ks = wg & 15, tile = wg >> 4;          // 16 tiles × 16 k-slabs
      const int Mt = tile & 1, ntl = tile >> 1;
      const int sd = ntl >> 2, Nt = ntl & 3, n0 = Nt * 128;
      const float* wa = sd ? p.fWrt : p.fWzt;
      const float* wb = sd ? p.fWrm : p.fWzm;
      float* part = ws + OFF_PB + tile * (16 * 4096);
      gemm_job<JB, 64>(p, sm, t, nullptr, sd, Mt * 32, n0, ks * 64,
                       wa, Hd, wb, Hd, Hd, part + ks * 4096);
      tile_wait(ws, 32 + tile, 16u * (unsigned)t);
      if (tid < 128) {
        const int e0 = (ks * 128 + tid) * 2;
        float2 s = redsumN(part, e0, 16);
        const int c = e0 & 127, brow = Mt * 32 + (e0 >> 7), col = n0 + c;
        const int base = brow * Hd + col;
        const float* bias = sd ? p.frb : p.fzb;
        float2 bv = *(const float2*)&bias[col];
        float2 g = make_float2(sig1(s.x + bv.x), sig1(s.y + bv.y));
        if (sd == 0) {
          st2v(ws + OFF_F + base, g);                  // z
        } else {                                       // r -> R·H = (r*Rt+(1-r)*Rm)*H(t-1)
          float2 rt = ld2v(ws + OFF_G + 1 * Bb * Hd + base);
          float2 rm = ld2v(ws + OFF_G + 3 * Bb * Hd + base);
          float2 ho = ld2v(ws + OFF_HB + ((t - 1) & 1) * Bb * Hd + base);
          st2v(ws + OFF_F + Bb * Hd + base,
               make_float2((g.x * rt.x + (1.f - g.x) * rm.x) * ho.x,
                           (g.y * rt.y + (1.f - g.y) * rm.y) * ho.y));
        }
      }
    }
    gbar(ws, wg, ++bt);
    // ---------- phase C: H̃ GEMM + H(t) materialize + out; X-mix(t+1) ----------
    if (wg < 64) {
      const int ks = wg & 7, tile = wg >> 3;           // 8 tiles × 8 k-slabs
      const int Mt = tile & 1, Nt = tile >> 1, n0 = Nt * 128;
      float* part = ws + OFF_PC + tile * (8 * 4096);
      gemm_job<JCH, 96>(p, sm, t, nullptr, 0, Mt * 32, n0, ks * 96,
                        p.Wxh, Hd, p.Whh, Hd, Ii, part + ks * 4096);
      tile_wait(ws, 48 + tile, 8u * (unsigned)t);
      const int e0 = (ks * 256 + tid) * 2;
      float2 s = redsumN(part, e0, 8);
      const int c = e0 & 127, brow = Mt * 32 + (e0 >> 7), col = n0 + c;
      float2 bv = *(const float2*)&p.bh[col];
      float ht0 = tanh1(s.x + bv.x), ht1 = tanh1(s.y + bv.y);
      const int base = brow * Hd + col;
      float2 zf = ld2v(ws + OFF_F + base);
      float2 zt = ld2v(ws + OFF_G + base);
      float2 zm = ld2v(ws + OFF_G + 2 * Bb * Hd + base);
      float2 ho = ld2v(ws + OFF_HB + ((t - 1) & 1) * Bb * Hd + base);
      float Z0 = zf.x * zt.x + (1.f - zf.x) * zm.x;
      float Z1 = zf.y * zt.y + (1.f - zf.y) * zm.y;
      float2 hn = make_float2(Z0 * ho.x + (1.f - Z0) * ht0, Z1 * ho.y + (1.f - Z1) * ht1);
      st2v(ws + OFF_HB + (t & 1) * Bb * Hd + base, hn);
      *(float2*)&p.out[(brow * Tt + (t - 1)) * Hd + col] = hn;
      if (t == Tt) *(float2*)&p.out[Bb * Tt * Hd + brow * Hd + col] = hn;
    } else if (wg < 96 && t < Tt) {
      const int w2 = wg - 64;
      const int ks = w2 & 7, tile = w2 >> 3;           // 4 tiles × 8 k-slabs
      const int Mt = tile & 1, Nt = tile >> 1, n0 = Nt * 128;
      float* part = ws + OFF_PX + tile * (8 * 4096);
      gemm_job<JX, 64>(p, sm, t, nullptr, 0, Mt * 32, n0, ks * 64,
                       p.fWxt, Ii, p.fWxm, Ii, Ii, part + ks * 4096);
      tile_wait(ws, 56 + tile, 8u * (unsigned)(t + 1));
      const int e0 = (ks * 256 + tid) * 2;
      float2 s = redsumN(part, e0, 8);
      const int c = e0 & 127, brow = Mt * 32 + (e0 >> 7), col = n0 + c;
      float2 bv = *(const float2*)&p.fxb[col];
      float xg0 = sig1(s.x + bv.x), xg1 = sig1(s.y + bv.y);
      float2 xt = *(const float2*)&p.tt[(brow * Tt + t) * Ii + col];
      float2 xm = *(const float2*)&p.mark[(brow * Tt + t) * Ii + col];
      st2v(ws + OFF_XB + ((t + 1) & 1) * Bb * Ii + brow * Ii + col,
           make_float2(xg0 * xt.x + (1.f - xg0) * xm.x, xg1 * xt.y + (1.f - xg1) * xm.y));
    }
    gbar(ws, wg, ++bt);
  }
}

extern "C" void kernel_launch(void* const* d_in, const int* in_sizes, int n_in,
                              void* d_out, int out_size, void* d_ws, size_t ws_size,
                              hipStream_t stream) {
  P pr;
  pr.tt    = (const float*)d_in[0];
  pr.mark  = (const float*)d_in[1];
  pr.Wxz_t = (const float*)d_in[2];
  pr.Wxr_t = (const float*)d_in[3];
  pr.Wxz_m = (const float*)d_in[4];
  pr.Wxr_m = (const float*)d_in[5];
  pr.Wxh   = (const float*)d_in[6];
  pr.Whz_t = (const float*)d_in[7];
  pr.Whr_t = (const float*)d_in[8];
  pr.Whz_m = (const float*)d_in[9];
  pr.Whr_m = (const float*)d_in[10];
  pr.Whh   = (const float*)d_in[11];
  pr.bz_t  = (const float*)d_in[12];
  pr.br_t  = (const float*)d_in[13];
  pr.bz_m  = (const float*)d_in[14];
  pr.br_m  = (const float*)d_in[15];
  pr.bh    = (const float*)d_in[16];
  pr.fWrt  = (const float*)d_in[17];
  pr.fWrm  = (const float*)d_in[18];
  pr.fWzt  = (const float*)d_in[19];
  pr.fWzm  = (const float*)d_in[20];
  pr.fWxt  = (const float*)d_in[21];
  pr.fWxm  = (const float*)d_in[22];
  pr.frb   = (const float*)d_in[23];
  pr.fzb   = (const float*)d_in[24];
  pr.fxb   = (const float*)d_in[25];
  pr.out = (float*)d_out;
  pr.ws  = (float*)d_ws;

  hipLaunchKernelGGL(ggru_init, dim3(192), dim3(256), 0, stream, (float*)d_ws);

  void* args[] = { (void*)&pr };
  hipError_t err = hipLaunchCooperativeKernel((const void*)ggru_persist,
                                              dim3(NWG), dim3(NTHR),
                                              args, (unsigned)SMEM_BYTES, stream);
  if (err != hipSuccess) {
    hipLaunchKernelGGL(ggru_persist, dim3(NWG), dim3(NTHR), SMEM_BYTES, stream, pr);
  }
}